// Round 15
// baseline (53.773 us; speedup 1.0000x reference)
//
#include <hip/hip_runtime.h>

#define HOP 512
#define NBINS 84
#define MT 16                 // time rows per M-tile (MFMA M)
#define BLOCK 256             // 4 waves
#define WPAD 11360            // repacked W row stride in elems (= 355*32)
#define WROWS 176             // 168 live rows (r'=2k+ri) + 8 zero rows
#define AUD_BYTES 40960       // staged window bytes (20480 bf16 samples, 10*4096)
#define NSLOT 7
#define LDS_BYTES (AUD_BYTES + NSLOT * 256 * 4)
#define ADEPTH 4              // A (LDS) ring depth: 4 MFMAs ~160cyc > LDS ~120cyc
#define BDEPTH 8              // B (global) ring depth: 8 MFMAs ~320cyc > L2 ~250cyc
#define PADT 675840           // padded samples per batch (165*4096)
#define ABYTES 1351680        // PADT*2 bytes, = 165*8192 (8192-aligned stride)
#define ACHUNKS (ABYTES / 16) // 84480 16-byte chunks per batch

typedef __attribute__((ext_vector_type(8))) short short8v;
typedef __attribute__((ext_vector_type(4))) float f32x4;

// Compile-time schedule. N-tile j covers bins 8j..8j+7 as 16 cols r'=2k+ri;
// K-extent ksteps[j] = ceil(len(8j)/32) = {355,224,141,89,56,36,23,14,9,6,4}.
// Two half-blocks per M-tile; LPT gives 118-121 ksteps per wave.
// Item = {tile, s0, s1, slot}; slot>=0 -> LDS partial; tile<0 -> unused.
__constant__ int SCHED[2][4][4][4] = {
    {   // half 0: tile0 split x3 (slots 0,1,2) + tiles 3,6,9
        {{0,   0, 118,  0}, {-1, 0, 0, -1}, {-1, 0, 0, -1}, {-1, 0, 0, -1}},
        {{0, 118, 236,  1}, {-1, 0, 0, -1}, {-1, 0, 0, -1}, {-1, 0, 0, -1}},
        {{0, 236, 355,  2}, {-1, 0, 0, -1}, {-1, 0, 0, -1}, {-1, 0, 0, -1}},
        {{3,   0,  89, -1}, { 6, 0, 23, -1}, { 9, 0, 6, -1}, {-1, 0, 0, -1}},
    },
    {   // half 1: tile1 split x2 (slots 3,4), tile2 split x2 (slots 5,6) + rest
        {{1,   0, 121,  3}, {-1, 0, 0, -1}, {-1, 0, 0, -1}, {-1, 0, 0, -1}},
        {{1, 121, 224,  4}, { 7, 0, 14, -1}, {10, 0, 4, -1}, {-1, 0, 0, -1}},
        {{2,   0, 121,  5}, {-1, 0, 0, -1}, {-1, 0, 0, -1}, {-1, 0, 0, -1}},
        {{2, 121, 141,  6}, { 4, 0, 56, -1}, { 5, 0, 36, -1}, { 8, 0, 9, -1}},
    },
};

__device__ __forceinline__ unsigned short f2bf(float f) {
    union { float f; unsigned u; } v; v.f = f;
    unsigned r = v.u + 0x7FFFu + ((v.u >> 16) & 1u);  // RNE
    return (unsigned short)(r >> 16);
}

// XOR swizzle: bits 4-6 ^= bits 10-12. Involution; bijective per 1KB block;
// invariant under adding any multiple of 8192 (window/batch bases are).
__device__ __forceinline__ int swz(int byte) {
    return byte ^ (((byte >> 10) & 7) << 4);
}

// Repack kr/ki into bf16 wb[r'][WPAD], r'=2k+ri; zero pad cols/rows.
// EXACT round-8 version — known-good under graph replay. Do not touch.
__global__ void cqt_repack_bf16(const float* __restrict__ kr,
                                const float* __restrict__ ki,
                                unsigned short* __restrict__ wb, int max_win) {
    int total = WROWS * WPAD;
    for (int idx = blockIdx.x * blockDim.x + threadIdx.x; idx < total;
         idx += gridDim.x * blockDim.x) {
        int r = idx / WPAD, c = idx % WPAD;
        float v = 0.0f;
        if (r < 2 * NBINS && c < max_win) {
            int k = r >> 1;
            v = (r & 1) ? ki[(size_t)k * max_win + c] : kr[(size_t)k * max_win + c];
        }
        wb[idx] = f2bf(v);
    }
}

// Convert audio fp32 -> bf16, PRE-SWIZZLED, zero-padded to PADT per batch.
// EXACT round-12 version — passed post-timing validation. Do not touch.
__global__ void cqt_prep_audio(const float* __restrict__ audio,
                               unsigned char* __restrict__ awb, int T, int B) {
    int total = B * ACHUNKS;
    for (int idx = blockIdx.x * blockDim.x + threadIdx.x; idx < total;
         idx += gridDim.x * blockDim.x) {
        int b = idx / ACHUNKS;
        int ch = idx % ACHUNKS;
        const float* ab = audio + (size_t)b * T;
        long s0 = 8L * ch;
        float f[8];
        if (s0 + 7 < T) {
            float4 x0 = *reinterpret_cast<const float4*>(ab + s0);
            float4 x1 = *reinterpret_cast<const float4*>(ab + s0 + 4);
            f[0] = x0.x; f[1] = x0.y; f[2] = x0.z; f[3] = x0.w;
            f[4] = x1.x; f[5] = x1.y; f[6] = x1.z; f[7] = x1.w;
        } else {
#pragma unroll
            for (int e = 0; e < 8; ++e) f[e] = (s0 + e < T) ? ab[s0 + e] : 0.0f;
        }
        uint4 w;
        w.x = (unsigned)f2bf(f[0]) | ((unsigned)f2bf(f[1]) << 16);
        w.y = (unsigned)f2bf(f[2]) | ((unsigned)f2bf(f[3]) << 16);
        w.z = (unsigned)f2bf(f[4]) | ((unsigned)f2bf(f[5]) << 16);
        w.w = (unsigned)f2bf(f[6]) | ((unsigned)f2bf(f[7]) << 16);
        *reinterpret_cast<uint4*>(awb + (size_t)b * ABYTES + swz(16 * ch)) = w;
    }
}

// asm-pinned loads. Over-issue past s1-1 is safe: A stays < AUD_BYTES
// (max step s1+3 -> 15408+64*358 = 38320), B stays inside wb (spills into
// the following row's columns); over-issued values are never consumed.
#define ISSUE_A(d_, sp_)                                                      \
    do {                                                                      \
        unsigned aoff_ = (unsigned)swz(abase + 64 * (sp_));                   \
        asm volatile("ds_read_b128 %0, %1" : "=v"(aR[d_]) : "v"(aoff_));      \
    } while (0)
#define ISSUE_B(d_, sp_)                                                      \
    do {                                                                      \
        const unsigned short* bp_ = brow + 32 * (sp_);                        \
        asm volatile("global_load_dwordx4 %0, %1, off"                        \
                     : "=v"(bR[d_]) : "v"(bp_));                              \
    } while (0)

__global__ __launch_bounds__(BLOCK, 4) void cqt_mfma(
    const unsigned char* __restrict__ awb, const unsigned short* __restrict__ wb,
    float* __restrict__ out, int nb, int mtiles) {
    extern __shared__ char smem[];
    float* part = (float*)(smem + AUD_BYTES);

    int bid = blockIdx.x;
    int half = bid & 1;
    int mb = bid >> 1;
    int m = mb % mtiles;
    int b = mb / mtiles;
    int tid = (int)threadIdx.x;

    // ---- stage window: pure linear copy of pre-swizzled bf16 (zero VALU) ----
    {
        const unsigned char* asrc = awb + (size_t)b * ABYTES + (size_t)m * 16384;
#pragma unroll
        for (int i = 0; i < AUD_BYTES / 4096; ++i) {
            int off = i * 4096 + tid * 16;  // lds dest: uniform base + lane*16
            __builtin_amdgcn_global_load_lds(
                (const __attribute__((address_space(1))) unsigned int*)(asrc + off),
                (__attribute__((address_space(3))) unsigned int*)(smem + i * 4096 +
                                                                  (tid & ~63) * 16),
                16, 0, 0);
        }
    }
    __syncthreads();  // drains vmcnt/lgkmcnt -> LDS window complete

    int wave = tid >> 6;
    int lane = tid & 63;
    int l15 = lane & 15;          // A: time row; B: col r' offset; D: col
    int q = lane >> 4;            // k-subchunk selector
    int abase = 1024 * l15 + 16 * q;  // byte base of A-frag at s=0

#pragma unroll
    for (int it = 0; it < 4; ++it) {
        int tile = SCHED[half][wave][it][0];
        if (tile < 0) break;
        int s0 = SCHED[half][wave][it][1];
        int s1 = SCHED[half][wave][it][2];
        int slot = SCHED[half][wave][it][3];

        const unsigned short* brow =
            wb + (size_t)(16 * tile + l15) * WPAD + 8 * q;

        f32x4 acc = {0.0f, 0.0f, 0.0f, 0.0f};
        f32x4 acc2 = {0.0f, 0.0f, 0.0f, 0.0f};

        // Drain to a clean counter state before the ring prologue.
        asm volatile("s_waitcnt vmcnt(0) lgkmcnt(0)");
        __builtin_amdgcn_sched_barrier(0);

        // A-ring depth 4 + B-ring depth 8 = 48 ring VGPRs (fits the 128 cap
        // WITHOUT spills — round 13/14's 128-VGPR ring forced the allocator
        // to spill asm-pending registers, which reads them before the load
        // lands; that was the 5.8e-3 deterministic error).
        short8v aR[ADEPTH], bR[BDEPTH];
#pragma unroll
        for (int d = 0; d < BDEPTH; ++d) {
            if (d < ADEPTH) ISSUE_A(d, s0 + d);
            ISSUE_B(d, s0 + d);
        }

        int s = s0;
        while (s + BDEPTH <= s1) {
#pragma unroll
            for (int d = 0; d < BDEPTH; ++d) {
                // Oldest A (step s+d) and oldest B (step s+d) retired:
                // DS retires in-order among DS; vmcnt decrements in issue
                // order; stray SMEM/store ops only add retirements.
                asm volatile("s_waitcnt vmcnt(7) lgkmcnt(3)");
                __builtin_amdgcn_sched_barrier(0);
                if (d & 1)
                    acc2 = __builtin_amdgcn_mfma_f32_16x16x32_bf16(aR[d & 3], bR[d], acc2, 0, 0, 0);
                else
                    acc = __builtin_amdgcn_mfma_f32_16x16x32_bf16(aR[d & 3], bR[d], acc, 0, 0, 0);
                ISSUE_A(d & 3, s + d + ADEPTH);
                ISSUE_B(d, s + d + BDEPTH);
            }
            s += BDEPTH;
        }
        // Epilogue: drain, then plain C++ LDS reads (compiler-managed waits).
        asm volatile("s_waitcnt vmcnt(0) lgkmcnt(0)");
        __builtin_amdgcn_sched_barrier(0);
#pragma unroll
        for (int d = 0; d < BDEPTH; ++d) {
            if (s + d < s1) {
                short8v a = *reinterpret_cast<const short8v*>(
                    smem + swz(abase + 64 * (s + d)));
                if (d & 1)
                    acc2 = __builtin_amdgcn_mfma_f32_16x16x32_bf16(a, bR[d], acc2, 0, 0, 0);
                else
                    acc = __builtin_amdgcn_mfma_f32_16x16x32_bf16(a, bR[d], acc, 0, 0, 0);
            }
        }
        acc = acc + acc2;

        if (slot >= 0) {
#pragma unroll
            for (int i = 0; i < 4; ++i)
                part[slot * 256 + (4 * q + i) * 16 + l15] = acc[i];
        } else {
            int k = 8 * tile + (l15 >> 1);
            int ri = l15 & 1;
#pragma unroll
            for (int i = 0; i < 4; ++i) {
                int t = MT * m + 4 * q + i;
                if (t < nb && k < NBINS)
                    out[(((size_t)b * nb + t) * NBINS + k) * 2 + ri] = acc[i];
            }
        }
    }
    __syncthreads();

    // ---- combine split-tile partials (fixed order -> deterministic) ----
    if (half == 0) {
        int e = tid;  // 256 entries, tile 0 = slots 0+1+2
        float v = part[0 * 256 + e] + part[1 * 256 + e] + part[2 * 256 + e];
        int t = MT * m + (e >> 4);
        int k = (e & 15) >> 1, ri = e & 1;
        if (t < nb)
            out[(((size_t)b * nb + t) * NBINS + k) * 2 + ri] = v;
    } else {
        for (int e = tid; e < 512; e += BLOCK) {
            int ct = e >> 8, ee = e & 255;  // ct=0: tile1 (slots 3,4); ct=1: tile2 (5,6)
            float v = part[(3 + 2 * ct) * 256 + ee] + part[(4 + 2 * ct) * 256 + ee];
            int t = MT * m + (ee >> 4);
            int k = 8 * (1 + ct) + ((ee & 15) >> 1), ri = ee & 1;
            if (t < nb)
                out[(((size_t)b * nb + t) * NBINS + k) * 2 + ri] = v;
        }
    }
}

extern "C" void kernel_launch(void* const* d_in, const int* in_sizes, int n_in,
                              void* d_out, int out_size, void* d_ws, size_t ws_size,
                              hipStream_t stream) {
    const float* audio = (const float*)d_in[0];
    const float* kr = (const float*)d_in[1];
    const float* ki = (const float*)d_in[2];
    float* out = (float*)d_out;

    const int T = 661500;                    // from setup_inputs
    const int B = in_sizes[0] / T;           // 4
    const int max_win = in_sizes[1] / NBINS; // 11341
    const int nb = T / HOP + 1;              // 1292
    const int mtiles = (nb + MT - 1) / MT;   // 81

    size_t wb_bytes = (size_t)WROWS * WPAD * sizeof(unsigned short);  // ~4.0 MB
    size_t awb_off = ((wb_bytes + 8191) / 8192) * 8192;               // 8KB-aligned
    size_t need = awb_off + (size_t)B * ABYTES + 1024;                // +overread slack
    if (ws_size < need) return;  // ws was >=260MB in all rounds

    unsigned short* wbuf = (unsigned short*)d_ws;
    unsigned char* awb = (unsigned char*)d_ws + awb_off;

    cqt_repack_bf16<<<2048, BLOCK, 0, stream>>>(kr, ki, wbuf, max_win);
    cqt_prep_audio<<<1320, BLOCK, 0, stream>>>(audio, awb, T, B);

    dim3 grid(B * mtiles * 2), block(BLOCK);
    cqt_mfma<<<grid, block, LDS_BYTES, stream>>>(awb, wbuf, out, nb, mtiles);
}

// Round 16
// 47.722 us; speedup vs baseline: 1.1268x; 1.1268x over previous
//
#include <hip/hip_runtime.h>

#define HOP 512
#define NBINS 84
#define MT 32                 // time rows per block (2 MFMA row-halves)
#define BLOCK 256             // 4 waves
#define AUD_BYTES 57344       // staged window: 14*4096 B (27232 samples + slack)
#define NSLOT 7
#define LDS_BYTES (AUD_BYTES + NSLOT * 512 * 4)   // 71680
#define ADEPTH 4              // A ring depth per half
#define BDEPTH 8              // B ring depth
#define PADT 684032           // padded samples per batch (167*4096)
#define ABYTES 1368064        // PADT*2, = 167*8192 (8192-aligned stride)
#define ACHUNKS (ABYTES / 16) // 85504 16-byte chunks per batch
#define WTOT_E 489984         // packed wb total elems (~0.98 MB)
#define WSLACK 4096           // B over-issue slack after wb

typedef __attribute__((ext_vector_type(8))) short short8v;
typedef __attribute__((ext_vector_type(4))) float f32x4;

// Packed-wb geometry: tile j has 16 rows (r'=2k+ri, k=8j+row/2), row stride
// = ksteps[j]*32 elems, ksteps = {355,224,141,89,56,36,23,14,9,6,4}.
__constant__ int TOFF[12]  = {0, 181760, 296448, 368640, 414208, 442880,
                              461312, 473088, 480256, 484864, 487936, 489984};
__constant__ int TKS32[11] = {11360, 7168, 4512, 2848, 1792, 1152, 736,
                              448, 288, 192, 128};

// Compile-time schedule (unchanged from rounds 8-15; K-extents per tile as
// above; LPT onto 2 half-blocks x 4 waves = 118-121 ksteps/wave).
// Item = {tile, s0, s1, slot}; slot>=0 -> LDS partial; tile<0 -> unused.
__constant__ int SCHED[2][4][4][4] = {
    {   // half 0: tile0 split x3 (slots 0,1,2) + tiles 3,6,9
        {{0,   0, 118,  0}, {-1, 0, 0, -1}, {-1, 0, 0, -1}, {-1, 0, 0, -1}},
        {{0, 118, 236,  1}, {-1, 0, 0, -1}, {-1, 0, 0, -1}, {-1, 0, 0, -1}},
        {{0, 236, 355,  2}, {-1, 0, 0, -1}, {-1, 0, 0, -1}, {-1, 0, 0, -1}},
        {{3,   0,  89, -1}, { 6, 0, 23, -1}, { 9, 0, 6, -1}, {-1, 0, 0, -1}},
    },
    {   // half 1: tile1 split x2 (slots 3,4), tile2 split x2 (slots 5,6) + rest
        {{1,   0, 121,  3}, {-1, 0, 0, -1}, {-1, 0, 0, -1}, {-1, 0, 0, -1}},
        {{1, 121, 224,  4}, { 7, 0, 14, -1}, {10, 0, 4, -1}, {-1, 0, 0, -1}},
        {{2,   0, 121,  5}, {-1, 0, 0, -1}, {-1, 0, 0, -1}, {-1, 0, 0, -1}},
        {{2, 121, 141,  6}, { 4, 0, 56, -1}, { 5, 0, 36, -1}, { 8, 0, 9, -1}},
    },
};

__device__ __forceinline__ unsigned short f2bf(float f) {
    union { float f; unsigned u; } v; v.f = f;
    unsigned r = v.u + 0x7FFFu + ((v.u >> 16) & 1u);  // RNE
    return (unsigned short)(r >> 16);
}

// XOR swizzle: bits 4-6 ^= bits 10-12. Involution; bijective per 8KB frame;
// invariant under adding multiples of 8192 (window bases are 32768-aligned).
__device__ __forceinline__ int swz(int byte) {
    return byte ^ (((byte >> 10) & 7) << 4);
}

// Repack kr/ki into PACKED bf16 wb: tile-local row stride TKS32[t].
// 1D grid-stride + scalar stores (round-8-validated shape; the 2D variant
// caused an unexplained post-timing divergence in round 9 — avoid).
__global__ void cqt_repack_packed(const float* __restrict__ kr,
                                  const float* __restrict__ ki,
                                  unsigned short* __restrict__ wb, int max_win) {
    for (int idx = blockIdx.x * blockDim.x + threadIdx.x; idx < WTOT_E;
         idx += gridDim.x * blockDim.x) {
        int t = 0;
#pragma unroll
        for (int j = 1; j < 11; ++j)
            if (idx >= TOFF[j]) t = j;
        int local = idx - TOFF[t];
        int ks32 = TKS32[t];
        int row = (unsigned)local / (unsigned)ks32;
        int c = local - row * ks32;
        int k = 8 * t + (row >> 1);
        float v = 0.0f;
        if (k < NBINS && c < max_win)
            v = ((row & 1) ? ki : kr)[(size_t)k * max_win + c];
        wb[idx] = f2bf(v);
    }
}

// Convert audio fp32 -> bf16, PRE-SWIZZLED, zero-padded to PADT per batch.
// Structure identical to the round-12/15-validated version (bounds updated).
__global__ void cqt_prep_audio(const float* __restrict__ audio,
                               unsigned char* __restrict__ awb, int T, int B) {
    int total = B * ACHUNKS;
    for (int idx = blockIdx.x * blockDim.x + threadIdx.x; idx < total;
         idx += gridDim.x * blockDim.x) {
        int b = idx / ACHUNKS;
        int ch = idx % ACHUNKS;
        const float* ab = audio + (size_t)b * T;
        long s0 = 8L * ch;
        float f[8];
        if (s0 + 7 < T) {
            float4 x0 = *reinterpret_cast<const float4*>(ab + s0);
            float4 x1 = *reinterpret_cast<const float4*>(ab + s0 + 4);
            f[0] = x0.x; f[1] = x0.y; f[2] = x0.z; f[3] = x0.w;
            f[4] = x1.x; f[5] = x1.y; f[6] = x1.z; f[7] = x1.w;
        } else {
#pragma unroll
            for (int e = 0; e < 8; ++e) f[e] = (s0 + e < T) ? ab[s0 + e] : 0.0f;
        }
        uint4 w;
        w.x = (unsigned)f2bf(f[0]) | ((unsigned)f2bf(f[1]) << 16);
        w.y = (unsigned)f2bf(f[2]) | ((unsigned)f2bf(f[3]) << 16);
        w.z = (unsigned)f2bf(f[4]) | ((unsigned)f2bf(f[5]) << 16);
        w.w = (unsigned)f2bf(f[6]) | ((unsigned)f2bf(f[7]) << 16);
        *reinterpret_cast<uint4*>(awb + (size_t)b * ABYTES + swz(16 * ch)) = w;
    }
}

// asm-pinned loads. Over-issue past s1-1 is safe: A stays < AUD_BYTES
// (max 16384+15360+48+64*358+16 = 54720 <= 57344); B overruns its row into
// the next (in-bounds) or past wb end by <512B (covered by WSLACK);
// over-issued values are never consumed (guarded epilogue).
#define ISSUE_A0(d_, sp_)                                                     \
    do {                                                                      \
        unsigned ao_ = (unsigned)swz(abase + 64 * (sp_));                     \
        asm volatile("ds_read_b128 %0, %1" : "=v"(aR0[d_]) : "v"(ao_));       \
    } while (0)
#define ISSUE_A1(d_, sp_)                                                     \
    do {                                                                      \
        unsigned ao_ = (unsigned)swz(16384 + abase + 64 * (sp_));             \
        asm volatile("ds_read_b128 %0, %1" : "=v"(aR1[d_]) : "v"(ao_));       \
    } while (0)
#define ISSUE_B(d_, sp_)                                                      \
    do {                                                                      \
        const unsigned short* bp_ = brow + 32 * (sp_);                        \
        asm volatile("global_load_dwordx4 %0, %1, off"                        \
                     : "=v"(bR[d_]) : "v"(bp_));                              \
    } while (0)

__global__ __launch_bounds__(BLOCK, 4) void cqt_mfma(
    const unsigned char* __restrict__ awb, const unsigned short* __restrict__ wb,
    float* __restrict__ out, int nb, int mtiles) {
    extern __shared__ char smem[];
    float* part = (float*)(smem + AUD_BYTES);

    int bid = blockIdx.x;
    int half = bid & 1;
    int mb = bid >> 1;
    int m = mb % mtiles;
    int b = mb / mtiles;
    int tid = (int)threadIdx.x;

    // ---- stage 32-row window: linear copy of pre-swizzled bf16 ----
    {
        const unsigned char* asrc = awb + (size_t)b * ABYTES + (size_t)m * 32768;
#pragma unroll
        for (int i = 0; i < AUD_BYTES / 4096; ++i) {
            int off = i * 4096 + tid * 16;
            __builtin_amdgcn_global_load_lds(
                (const __attribute__((address_space(1))) unsigned int*)(asrc + off),
                (__attribute__((address_space(3))) unsigned int*)(smem + i * 4096 +
                                                                  (tid & ~63) * 16),
                16, 0, 0);
        }
    }
    __syncthreads();

    int wave = tid >> 6;
    int lane = tid & 63;
    int l15 = lane & 15;              // A: time row; B: col r'; D: col
    int q = lane >> 4;                // k-subchunk selector
    int abase = 1024 * l15 + 16 * q;  // byte base of low-half A-frag at s=0

#pragma unroll
    for (int it = 0; it < 4; ++it) {
        int tile = SCHED[half][wave][it][0];
        if (tile < 0) break;
        int s0 = SCHED[half][wave][it][1];
        int s1 = SCHED[half][wave][it][2];
        int slot = SCHED[half][wave][it][3];

        const unsigned short* brow = wb + TOFF[tile] + l15 * TKS32[tile] + 8 * q;

        f32x4 accL = {0.0f, 0.0f, 0.0f, 0.0f};
        f32x4 accH = {0.0f, 0.0f, 0.0f, 0.0f};

        // Clean counter state before the ring prologue.
        asm volatile("s_waitcnt vmcnt(0) lgkmcnt(0)");
        __builtin_amdgcn_sched_barrier(0);

        // Rings: 2 x A(depth4) + B(depth8) = 64 VGPRs — fits the 128 cap
        // without spills (round-13/14 lesson: spilled asm-pending regs are
        // read before the load lands).
        short8v aR0[ADEPTH], aR1[ADEPTH], bR[BDEPTH];
#pragma unroll
        for (int d = 0; d < BDEPTH; ++d) {
            if (d < ADEPTH) { ISSUE_A0(d, s0 + d); ISSUE_A1(d, s0 + d); }
            ISSUE_B(d, s0 + d);
        }

        int s = s0;
        while (s + BDEPTH <= s1) {
#pragma unroll
            for (int d = 0; d < BDEPTH; ++d) {
                // 8 DS outstanding (4 steps x 2 halves): <=6 left means both
                // of step s retired. vmcnt(7): oldest B retired.
                asm volatile("s_waitcnt vmcnt(7) lgkmcnt(6)");
                __builtin_amdgcn_sched_barrier(0);
                accL = __builtin_amdgcn_mfma_f32_16x16x32_bf16(aR0[d & 3], bR[d], accL, 0, 0, 0);
                accH = __builtin_amdgcn_mfma_f32_16x16x32_bf16(aR1[d & 3], bR[d], accH, 0, 0, 0);
                ISSUE_A0(d & 3, s + d + ADEPTH);
                ISSUE_A1(d & 3, s + d + ADEPTH);
                ISSUE_B(d, s + d + BDEPTH);
            }
            s += BDEPTH;
        }
        // Epilogue: drain, then compiler-managed LDS reads for the tail.
        asm volatile("s_waitcnt vmcnt(0) lgkmcnt(0)");
        __builtin_amdgcn_sched_barrier(0);
#pragma unroll
        for (int d = 0; d < BDEPTH; ++d) {
            if (s + d < s1) {
                short8v a0 = *reinterpret_cast<const short8v*>(
                    smem + swz(abase + 64 * (s + d)));
                short8v a1 = *reinterpret_cast<const short8v*>(
                    smem + swz(16384 + abase + 64 * (s + d)));
                accL = __builtin_amdgcn_mfma_f32_16x16x32_bf16(a0, bR[d], accL, 0, 0, 0);
                accH = __builtin_amdgcn_mfma_f32_16x16x32_bf16(a1, bR[d], accH, 0, 0, 0);
            }
        }

        if (slot >= 0) {
#pragma unroll
            for (int i = 0; i < 4; ++i) {
                part[slot * 512 + (4 * q + i) * 16 + l15] = accL[i];
                part[slot * 512 + 256 + (4 * q + i) * 16 + l15] = accH[i];
            }
        } else {
            int k = 8 * tile + (l15 >> 1);
            int ri = l15 & 1;
#pragma unroll
            for (int i = 0; i < 4; ++i) {
                int tL = MT * m + 4 * q + i;
                int tH = tL + 16;
                if (tL < nb && k < NBINS)
                    out[(((size_t)b * nb + tL) * NBINS + k) * 2 + ri] = accL[i];
                if (tH < nb && k < NBINS)
                    out[(((size_t)b * nb + tH) * NBINS + k) * 2 + ri] = accH[i];
            }
        }
    }
    __syncthreads();

    // ---- combine split-tile partials (fixed order -> deterministic) ----
    if (half == 0) {
        for (int e = tid; e < 512; e += BLOCK) {  // tile 0 = slots 0+1+2
            float v = part[0 * 512 + e] + part[1 * 512 + e] + part[2 * 512 + e];
            int h = e >> 8, ee = e & 255;
            int t = MT * m + 16 * h + (ee >> 4);
            int k = (ee & 15) >> 1, ri = ee & 1;
            if (t < nb)
                out[(((size_t)b * nb + t) * NBINS + k) * 2 + ri] = v;
        }
    } else {
        for (int e = tid; e < 1024; e += BLOCK) {  // tile1=slots3+4, tile2=5+6
            int ct = e >> 9, w = e & 511;
            float v = part[(3 + 2 * ct) * 512 + w] + part[(4 + 2 * ct) * 512 + w];
            int h = w >> 8, ee = w & 255;
            int t = MT * m + 16 * h + (ee >> 4);
            int k = 8 * (1 + ct) + ((ee & 15) >> 1), ri = ee & 1;
            if (t < nb)
                out[(((size_t)b * nb + t) * NBINS + k) * 2 + ri] = v;
        }
    }
}

extern "C" void kernel_launch(void* const* d_in, const int* in_sizes, int n_in,
                              void* d_out, int out_size, void* d_ws, size_t ws_size,
                              hipStream_t stream) {
    const float* audio = (const float*)d_in[0];
    const float* kr = (const float*)d_in[1];
    const float* ki = (const float*)d_in[2];
    float* out = (float*)d_out;

    const int T = 661500;                    // from setup_inputs
    const int B = in_sizes[0] / T;           // 4
    const int max_win = in_sizes[1] / NBINS; // 11341
    const int nb = T / HOP + 1;              // 1292
    const int mtiles = (nb + MT - 1) / MT;   // 41

    size_t wb_bytes = (size_t)WTOT_E * 2;                              // ~0.98 MB
    size_t awb_off = ((wb_bytes + WSLACK + 8191) / 8192) * 8192;       // 8KB-aligned
    size_t need = awb_off + (size_t)B * ABYTES + 1024;
    if (ws_size < need) return;  // ws was >=260MB in all rounds

    unsigned short* wbuf = (unsigned short*)d_ws;
    unsigned char* awb = (unsigned char*)d_ws + awb_off;

    cqt_repack_packed<<<1914, BLOCK, 0, stream>>>(kr, ki, wbuf, max_win);
    cqt_prep_audio<<<1336, BLOCK, 0, stream>>>(audio, awb, T, B);

    dim3 grid(B * mtiles * 2), block(BLOCK);
    cqt_mfma<<<grid, block, LDS_BYTES, stream>>>(awb, wbuf, out, nb, mtiles);
}